// Round 5
// baseline (113.422 us; speedup 1.0000x reference)
//
#include <hip/hip_runtime.h>
#include <hip/hip_bf16.h>
#include <math.h>

// Problem constants (fixed by reference setup_inputs)
#define BHALF 4096          // B
#define NROW 8192           // 2B
#define DIM 128             // D
#define INV_T 10.0f         // 1/temperature
#define K1 14.4269504088896f  // INV_T*log2(e): exp((v-1)*10) = 2^(v*K1 - K1)
#define NREP 4              // ABLATION: sweep executed NREP times (see R10 notes)

typedef short bf16x8 __attribute__((ext_vector_type(8)));   // 8 bf16 = 4 VGPRs
typedef float f32x4  __attribute__((ext_vector_type(4)));   // C/D frag

typedef const __attribute__((address_space(1))) void ga_void;
typedef __attribute__((address_space(3))) void ls_void;

// ---------------------------------------------------------------------------
// Kernel 1: row-normalize concat(view1, view2) -> e_bf16 (NROW x DIM);
// zero d_out and the two never-written partial slices. One wave per row.
// ---------------------------------------------------------------------------
__global__ __launch_bounds__(256) void normalize_kernel(
    const float* __restrict__ v1, const float* __restrict__ v2,
    __hip_bfloat16* __restrict__ e, float* __restrict__ rowpart,
    float* __restrict__ colpart, float* __restrict__ out) {
  int row  = blockIdx.x * 4 + (threadIdx.x >> 6);
  int lane = threadIdx.x & 63;
  const float* src = (row < BHALF) ? (v1 + (size_t)row * DIM)
                                   : (v2 + (size_t)(row - BHALF) * DIM);
  float2 x = ((const float2*)src)[lane];
  float ss = x.x * x.x + x.y * x.y;
#pragma unroll
  for (int off = 32; off > 0; off >>= 1) ss += __shfl_down(ss, off);
  ss = __shfl(ss, 0);
  float s = 1.0f / fmaxf(sqrtf(ss), 1e-8f);
  ((__hip_bfloat162*)(e + (size_t)row * DIM))[lane] =
      __float22bfloat162_rn(make_float2(x.x * s, x.y * s));
  // Zero the two partial slices no sim block writes:
  //   rowpart[32][4096..8192)  (rows >=4096 have no d=32 row-tile)
  //   colpart[31][0..4096)     (cols <4096 have no d=32 col-tile)
  const int t = blockIdx.x * 256 + threadIdx.x;
  if (t < 4096)      rowpart[(size_t)32 * NROW + 4096 + t] = 0.0f;
  else if (t < 8192) colpart[(size_t)31 * NROW + (t - 4096)] = 0.0f;
  if (t == 0) out[0] = 0.0f;
}

// ---------------------------------------------------------------------------
// Stage one 128-col strip of e (128 rows x 256 B) into LDS via
// global_load_lds(16B). LDS layout: [128 rows][16 chunks of 16B], chunk index
// XOR-swizzled by (row&7). LDS dest LINEAR (wave-uniform base + lane*16);
// swizzle applied by permuting the per-lane GLOBAL source chunk (rule #21).
// ---------------------------------------------------------------------------
__device__ __forceinline__ void stage_strip(const ushort* __restrict__ eC,
                                            ushort* BsBuf, int wave, int lane) {
#pragma unroll
  for (int j = 0; j < 8; ++j) {
    const int row    = wave * 32 + j * 4 + (lane >> 4);
    const int chunkp = lane & 15;                 // LDS chunk this lane fills
    const int gchunk = chunkp ^ (row & 7);        // global chunk it must hold
    const ushort* g  = eC + row * DIM + gchunk * 8;
    ushort* l        = BsBuf + (wave * 32 + j * 4) * 128;  // wave-uniform base
    __builtin_amdgcn_global_load_lds((ga_void*)g, (ls_void*)l, 16, 0, 0);
  }
}

// ---------------------------------------------------------------------------
// Symmetric MFMA sweep over one 128x128 tile. MODE semantics as R9.
// rsum ACCUMULATES across NREP calls (scaled 1/NREP in finalize);
// colred/posv are overwritten (idempotent, stay 1x).
// ---------------------------------------------------------------------------
template <int MODE>
__device__ __forceinline__ void sweep_tile(
    const ushort* __restrict__ Bs, const bf16x8 (&a_frag)[2][4],
    float (&rsum)[2][4], float (*colred)[128], float* __restrict__ posv,
    const int (&chunkOff)[4], int wave, int lane, int n, int quad,
    int rowStrip, int colStrip) {
  const int colBase = colStrip * 128;
#pragma unroll 1
  for (int sub = 0; sub < 8; ++sub) {
    const ushort* bp = Bs + (sub * 16 + n) * 128;
    bf16x8 b[4];
#pragma unroll
    for (int kk = 0; kk < 4; ++kk) b[kk] = *(const bf16x8*)(bp + chunkOff[kk]);
    float csum = 0.0f;
    const int lc = sub * 16 + n;
#pragma unroll
    for (int rf = 0; rf < 2; ++rf) {
      f32x4 acc = {0.f, 0.f, 0.f, 0.f};
#pragma unroll
      for (int kk = 0; kk < 4; ++kk)
        acc = __builtin_amdgcn_mfma_f32_16x16x32_bf16(a_frag[rf][kk], b[kk],
                                                      acc, 0, 0, 0);
      // C layout: row = quad*4 + reg, col = lane&15 (m89/m91 verified).
#pragma unroll
      for (int rr = 0; rr < 4; ++rr) {
        const int lr = wave * 32 + rf * 16 + quad * 4 + rr;
        const float val = acc[rr];
        // exp((val-1)/T) = 2^(val*K1 - K1): one v_fma + one v_exp_f32
        const float ex = __builtin_amdgcn_exp2f(val * K1 - K1);
        if (MODE == 0) {
          rsum[rf][rr] += (lr == lc) ? 0.0f : ex;       // mask true diagonal
        } else if (MODE == 1) {
          rsum[rf][rr] += ex;
          csum += ex;
        } else {                                        // partner tile
          const bool hit = (lr == lc);
          const float w = hit ? 2.0f : 1.0f;
          rsum[rf][rr] += w * ex;
          csum += w * ex;
          if (hit) {
            posv[rowStrip * 128 + lr] = val;            // row i (<4096)
            posv[colBase + lc] = val;                   // partner j = i^4096
          }
        }
      }
    }
    if (MODE != 0) {
      // col-sum over this wave's 32 rows -> LDS slot (overwrite; stays 1x).
      csum += __shfl_xor(csum, 16);
      csum += __shfl_xor(csum, 32);
      if (lane < 16) colred[wave][lc] = csum;
    }
  }
}

// ---------------------------------------------------------------------------
// Kernel 2: symmetric sim + exp-sum partials, zero atomics.
// ABLATION (R10): the sweep runs NREP=4 times. An asm-volatile zero offset
// per rep defeats CSE (otherwise identical MFMAs/ds_reads/exps fold away,
// rule #17). Purpose: sim = F + NREP*W becomes visible above the harness
// fill cutoff (~41.4us) with a full rocprof counter row; the total's delta
// splits fixed cost F from marginal tile-work W.
// ---------------------------------------------------------------------------
__global__ __launch_bounds__(256, 4) void sim_kernel(
    const ushort* __restrict__ e, float* __restrict__ rowpart,
    float* __restrict__ colpart, float* __restrict__ posv) {
  const int r = blockIdx.x;
  const int d = blockIdx.y;
  if (d == 32 && r >= 32) return;   // uniform: whole block exits, no barrier hazard
  const int c = (r + d) & 63;

  __shared__ ushort Bs[128 * 128] __attribute__((aligned(16)));
  __shared__ float colred[4][128];

  const int tid  = threadIdx.x;
  const int wave = tid >> 6;
  const int lane = tid & 63;
  const int n    = lane & 15;
  const int quad = lane >> 4;

  // Per-lane swizzled LDS chunk offsets (ushort units):
  int chunkOff[4];
#pragma unroll
  for (int kk = 0; kk < 4; ++kk)
    chunkOff[kk] = (((quad + 4 * kk) ^ (n & 7)) * 8);

  // Stage col strip (DMA flies under the A-frag loads below).
  stage_strip(e + (size_t)c * 128 * DIM, Bs, wave, lane);

  // A fragments: 2 row-frags x 4 k-steps, register-resident.
  bf16x8 a_frag[2][4];
  const int rowWave = r * 128 + wave * 32;
#pragma unroll
  for (int rf = 0; rf < 2; ++rf) {
    const ushort* rp = e + (size_t)(rowWave + rf * 16 + n) * DIM + quad * 8;
#pragma unroll
    for (int kk = 0; kk < 4; ++kk)
      a_frag[rf][kk] = *(const bf16x8*)(rp + kk * 32);
  }

  float rsum[2][4] = {{0.f, 0.f, 0.f, 0.f}, {0.f, 0.f, 0.f, 0.f}};
  __syncthreads();   // drains vmcnt(0): Bs ready

#pragma unroll 1
  for (int rep = 0; rep < NREP; ++rep) {
    int zofs;
    asm volatile("s_mov_b32 %0, 0" : "=s"(zofs));  // opaque 0: defeats CSE
    const ushort* BsR = Bs + zofs;
    if (d == 0)
      sweep_tile<0>(BsR, a_frag, rsum, colred, posv, chunkOff, wave, lane, n,
                    quad, r, c);
    else if (d == 32)
      sweep_tile<2>(BsR, a_frag, rsum, colred, posv, chunkOff, wave, lane, n,
                    quad, r, c);
    else
      sweep_tile<1>(BsR, a_frag, rsum, colred, posv, chunkOff, wave, lane, n,
                    quad, r, c);
  }

  // Row sums (NREP-scaled): reduce across 16 col-lanes, direct store.
#pragma unroll
  for (int rf = 0; rf < 2; ++rf)
#pragma unroll
    for (int rr = 0; rr < 4; ++rr) {
      float v = rsum[rf][rr];
      v += __shfl_xor(v, 1);
      v += __shfl_xor(v, 2);
      v += __shfl_xor(v, 4);
      v += __shfl_xor(v, 8);
      if (n == 0)
        rowpart[(size_t)d * NROW + rowWave + rf * 16 + quad * 4 + rr] = v;
    }

  // Col sums (1x): cross-wave reduce in LDS, direct store.
  if (d != 0) {
    __syncthreads();
    if (tid < 128) {
      float s = colred[0][tid] + colred[1][tid] + colred[2][tid] +
                colred[3][tid];
      colpart[(size_t)(d - 1) * NROW + c * 128 + tid] = s;
    }
  }
}

// ---------------------------------------------------------------------------
// Kernel 3: S_i = (1/NREP)*sum_d rowpart[d][i] + sum_s colpart[s][i];
// loss_i = log(S_i) + (1-pos_i)/T ; out = mean (32 atomic partials).
// ---------------------------------------------------------------------------
__global__ __launch_bounds__(256) void finalize_kernel(
    const float* __restrict__ rowpart, const float* __restrict__ colpart,
    const float* __restrict__ posv, float* __restrict__ out) {
  __shared__ float red[4];
  const int i = blockIdx.x * 256 + threadIdx.x;
  float Sr = 0.0f, Sc = 0.0f;
#pragma unroll
  for (int dd = 0; dd < 33; ++dd) Sr += rowpart[(size_t)dd * NROW + i];
#pragma unroll
  for (int ss = 0; ss < 32; ++ss) Sc += colpart[(size_t)ss * NROW + i];
  const float S = Sr * (1.0f / NREP) + Sc;
  float l = __logf(S) + (1.0f - posv[i]) * INV_T;
#pragma unroll
  for (int off = 32; off > 0; off >>= 1) l += __shfl_down(l, off);
  if ((threadIdx.x & 63) == 0) red[threadIdx.x >> 6] = l;
  __syncthreads();
  if (threadIdx.x == 0)
    atomicAdd(out, (red[0] + red[1] + red[2] + red[3]) * (1.0f / NROW));
}

// ---------------------------------------------------------------------------
extern "C" void kernel_launch(void* const* d_in, const int* in_sizes, int n_in,
                              void* d_out, int out_size, void* d_ws, size_t ws_size,
                              hipStream_t stream) {
  const float* v1 = (const float*)d_in[0];
  const float* v2 = (const float*)d_in[1];
  float* out = (float*)d_out;

  __hip_bfloat16* e = (__hip_bfloat16*)d_ws;          // NROW*DIM bf16 (2 MB)
  float* rowpart = (float*)(e + (size_t)NROW * DIM);  // 33*NROW floats
  float* colpart = rowpart + (size_t)33 * NROW;       // 32*NROW floats
  float* posv    = colpart + (size_t)32 * NROW;       // NROW floats

  normalize_kernel<<<NROW / 4, 256, 0, stream>>>(v1, v2, e, rowpart, colpart,
                                                 out);
  dim3 grid(64, 33);
  sim_kernel<<<grid, 256, 0, stream>>>((const ushort*)e, rowpart, colpart,
                                       posv);
  finalize_kernel<<<32, 256, 0, stream>>>(rowpart, colpart, posv, out);
}

// Round 6
// 81.813 us; speedup vs baseline: 1.3863x; 1.3863x over previous
//
#include <hip/hip_runtime.h>
#include <hip/hip_bf16.h>
#include <math.h>

// Problem constants (fixed by reference setup_inputs)
#define BHALF 4096          // B
#define NROW 8192           // 2B
#define DIM 128             // D
#define INV_T 10.0f         // 1/temperature
#define K1 14.4269504088896f  // INV_T*log2(e): exp((v-1)*10) = 2^(v*K1 - K1)

typedef short bf16x8 __attribute__((ext_vector_type(8)));   // 8 bf16 = 4 VGPRs
typedef float f32x4  __attribute__((ext_vector_type(4)));   // C/D frag

typedef const __attribute__((address_space(1))) void ga_void;
typedef __attribute__((address_space(3))) void ls_void;

// ---------------------------------------------------------------------------
// Kernel 1: row-normalize concat(view1, view2) -> e_bf16 (NROW x DIM);
// zero d_out and colpart slice 31 cols [0,4096) (never written by sim).
// ---------------------------------------------------------------------------
__global__ __launch_bounds__(256) void normalize_kernel(
    const float* __restrict__ v1, const float* __restrict__ v2,
    __hip_bfloat16* __restrict__ e, float* __restrict__ colpart,
    float* __restrict__ out) {
  int row  = blockIdx.x * 4 + (threadIdx.x >> 6);
  int lane = threadIdx.x & 63;
  const float* src = (row < BHALF) ? (v1 + (size_t)row * DIM)
                                   : (v2 + (size_t)(row - BHALF) * DIM);
  float2 x = ((const float2*)src)[lane];
  float ss = x.x * x.x + x.y * x.y;
#pragma unroll
  for (int off = 32; off > 0; off >>= 1) ss += __shfl_down(ss, off);
  ss = __shfl(ss, 0);
  float s = 1.0f / fmaxf(sqrtf(ss), 1e-8f);
  ((__hip_bfloat162*)(e + (size_t)row * DIM))[lane] =
      __float22bfloat162_rn(make_float2(x.x * s, x.y * s));
  const int t = blockIdx.x * 256 + threadIdx.x;
  if (t < 4096) colpart[(size_t)31 * NROW + t] = 0.0f;  // d=32 covers cols>=4096 only
  if (t == 0) out[0] = 0.0f;
}

// ---------------------------------------------------------------------------
// Stage one 128-col strip of e (128 rows x 256 B) into LDS via
// global_load_lds(16B). LDS layout: [128 rows][16 chunks of 16B], chunk
// index XOR-swizzled by (row&15) — R10 PMC showed the old (row&7) swizzle
// left 4.26M conflict cycles (8 lanes/bank-quad); the 4-bit XOR spreads a
// wave's b128 reads over all 16 chunks (16-lane group covers each chunk
// exactly once -> conflict-free). Rule #21: LDS dest LINEAR (wave-uniform
// base + lane*16); swizzle applied by permuting the per-lane GLOBAL source
// chunk (XOR involution). Each wave stages 32 rows.
// ---------------------------------------------------------------------------
__device__ __forceinline__ void stage_strip(const ushort* __restrict__ eC,
                                            ushort* BsBuf, int wave, int lane) {
#pragma unroll
  for (int j = 0; j < 8; ++j) {
    const int row    = wave * 32 + j * 4 + (lane >> 4);
    const int gchunk = (lane & 15) ^ (row & 15);
    const ushort* g  = eC + row * DIM + gchunk * 8;
    ushort* l        = BsBuf + (wave * 32 + j * 4) * 128;  // wave-uniform base
    __builtin_amdgcn_global_load_lds((ga_void*)g, (ls_void*)l, 16, 0, 0);
  }
}

// ---------------------------------------------------------------------------
// One 128x128 tile sweep, sub-loop FULLY UNROLLED (R10: unroll-1 cost ~3x
// VALU in address/index recompute; unrolled, ds offsets are immediates).
// domask (d==0): mask the true diagonal.  dopos (d==32): local diagonal =
// positive, weight 2 + posv stores.  The diagonal can only live in fragment
// sub == 2*wave + rf -> scalar-guarded; all other fragments run the lean
// path (fma + exp2 + 2 adds per element).  Col-sums -> colred[wave][lc]
// (LDS, no atomics; R7 lesson: device atomics serialize ~15us).
// ---------------------------------------------------------------------------
__device__ __forceinline__ void sweep_tile(
    const ushort* __restrict__ Bs, float* __restrict__ colred,
    const bf16x8 (&a_frag)[2][4], float (&rsum)[2][4],
    const int (&chunkOff)[4], bool domask, bool dopos, int wave, int lane,
    int n, int quad, int rowStrip, int colBase, float* __restrict__ posv) {
#pragma unroll
  for (int sub = 0; sub < 8; ++sub) {
    const ushort* bp = Bs + (sub * 16 + n) * 128;
    bf16x8 b[4];
#pragma unroll
    for (int kk = 0; kk < 4; ++kk) b[kk] = *(const bf16x8*)(bp + chunkOff[kk]);
    float csum = 0.0f;
#pragma unroll
    for (int rf = 0; rf < 2; ++rf) {
      f32x4 acc = {0.f, 0.f, 0.f, 0.f};
#pragma unroll
      for (int kk = 0; kk < 4; ++kk)
        acc = __builtin_amdgcn_mfma_f32_16x16x32_bf16(a_frag[rf][kk], b[kk],
                                                      acc, 0, 0, 0);
      // C layout: row = quad*4 + reg, col = lane&15 (m89/m91 verified).
      if ((domask | dopos) && sub == 2 * wave + rf) {
        // Fragment that carries the tile-local diagonal (scalar-guarded).
#pragma unroll
        for (int rr = 0; rr < 4; ++rr) {
          const float val = acc[rr];
          const float ex = __builtin_amdgcn_exp2f(__builtin_fmaf(val, K1, -K1));
          const bool hit = (n == quad * 4 + rr);
          if (domask) {
            rsum[rf][rr] += hit ? 0.0f : ex;   // mask self-similarity
          } else {                              // dopos: weight 2 + posv
            const float exw = hit ? 2.0f * ex : ex;
            rsum[rf][rr] += exw;
            csum += exw;
            if (hit) {
              posv[rowStrip * 128 + wave * 32 + rf * 16 + quad * 4 + rr] = val;
              posv[colBase + sub * 16 + n] = val;
            }
          }
        }
      } else {
#pragma unroll
        for (int rr = 0; rr < 4; ++rr) {
          const float ex =
              __builtin_amdgcn_exp2f(__builtin_fmaf(acc[rr], K1, -K1));
          rsum[rf][rr] += ex;
          csum += ex;
        }
      }
    }
    // col-sum over this wave's 32 rows -> LDS slot (overwrite, no atomic).
    csum += __shfl_xor(csum, 16);
    csum += __shfl_xor(csum, 32);
    if (lane < 16) colred[wave * 128 + sub * 16 + n] = csum;
  }
}

// ---------------------------------------------------------------------------
// Kernel 2: symmetric sim + exp-sum partials, zero atomics, FAT BLOCKS.
// Grid (64, 8) = 512 blocks = 2/CU, one round (R10: F~28.6us of the
// single-tile 2080-block layout was per-block prologue latency; 4-5 tiles
// per block amortize it). Block (r,h): d in {4h..4h+3}, plus d=32 for
// (h==0, r<32). Double-buffered staging in two NAMED __shared__ arrays
// (static alias disambiguation: DMA->Bs1 can't force a vmcnt wait before
// ds_read<-Bs0). One __syncthreads per tile (drains DMA + colred).
// ---------------------------------------------------------------------------
__global__ __launch_bounds__(256, 2) void sim_kernel(
    const ushort* __restrict__ e, float* __restrict__ rowpart,
    float* __restrict__ colpart, float* __restrict__ posv) {
  const int r = blockIdx.x;
  const int h = blockIdx.y;

  __shared__ ushort Bs0[128 * 128] __attribute__((aligned(16)));
  __shared__ ushort Bs1[128 * 128] __attribute__((aligned(16)));
  __shared__ float colA[512];
  __shared__ float colB[512];

  const int tid  = threadIdx.x;
  const int wave = tid >> 6;
  const int lane = tid & 63;
  const int n    = lane & 15;
  const int quad = lane >> 4;

  // Per-lane swizzled LDS chunk offsets (ushort units), &15 swizzle:
  int chunkOff[4];
#pragma unroll
  for (int kk = 0; kk < 4; ++kk)
    chunkOff[kk] = (((quad + 4 * kk) ^ n) * 8);

  const int NT = (h == 0 && r < 32) ? 5 : 4;   // tiles this block owns

  // Prologue: stage first strip; A-frag loads fly under the DMA.
  stage_strip(e + (size_t)((r + 4 * h) & 63) * 128 * DIM, Bs0, wave, lane);

  bf16x8 a_frag[2][4];
  const int rowWave = r * 128 + wave * 32;
#pragma unroll
  for (int rf = 0; rf < 2; ++rf) {
    const ushort* rp = e + (size_t)(rowWave + rf * 16 + n) * DIM + quad * 8;
#pragma unroll
    for (int kk = 0; kk < 4; ++kk)
      a_frag[rf][kk] = *(const bf16x8*)(rp + kk * 32);
  }

  float rsum[2][4] = {{0.f, 0.f, 0.f, 0.f}, {0.f, 0.f, 0.f, 0.f}};
  __syncthreads();   // Bs0 ready (drains vmcnt)

#pragma unroll 1
  for (int i = 0; i < NT; i += 2) {
    {  // ---- phase A: compute Bs0, stage into Bs1 ----
      const int d = (i < 4) ? 4 * h + i : 32;
      const int c = (r + d) & 63;
      if (i + 1 < NT) {
        const int dn = (i + 1 < 4) ? 4 * h + i + 1 : 32;
        stage_strip(e + (size_t)((r + dn) & 63) * 128 * DIM, Bs1, wave, lane);
      }
      sweep_tile(Bs0, colA, a_frag, rsum, chunkOff, d == 0, d == 32, wave,
                 lane, n, quad, r, c * 128, posv);
      __syncthreads();  // Bs1 ready; colA complete
      if (d != 0 && tid < 128) {
        float s = colA[tid] + colA[128 + tid] + colA[256 + tid] +
                  colA[384 + tid];
        colpart[(size_t)(d - 1) * NROW + c * 128 + tid] = s;
      }
    }
    if (i + 1 >= NT) break;
    {  // ---- phase B: compute Bs1, stage into Bs0 ----
      const int d = (i + 1 < 4) ? 4 * h + i + 1 : 32;
      const int c = (r + d) & 63;
      if (i + 2 < NT) {
        const int dn = (i + 2 < 4) ? 4 * h + i + 2 : 32;
        stage_strip(e + (size_t)((r + dn) & 63) * 128 * DIM, Bs0, wave, lane);
      }
      sweep_tile(Bs1, colB, a_frag, rsum, chunkOff, d == 0, d == 32, wave,
                 lane, n, quad, r, c * 128, posv);
      __syncthreads();  // Bs0 ready; colB complete
      if (d != 0 && tid < 128) {
        float s = colB[tid] + colB[128 + tid] + colB[256 + tid] +
                  colB[384 + tid];
        colpart[(size_t)(d - 1) * NROW + c * 128 + tid] = s;
      }
    }
  }

  // Row sums over this block's 4-5 tiles: reduce across 16 col-lanes,
  // direct store to slice h (unique slot; every (h,row) written once).
#pragma unroll
  for (int rf = 0; rf < 2; ++rf)
#pragma unroll
    for (int rr = 0; rr < 4; ++rr) {
      float v = rsum[rf][rr];
      v += __shfl_xor(v, 1);
      v += __shfl_xor(v, 2);
      v += __shfl_xor(v, 4);
      v += __shfl_xor(v, 8);
      if (n == 0)
        rowpart[(size_t)h * NROW + rowWave + rf * 16 + quad * 4 + rr] = v;
    }
}

// ---------------------------------------------------------------------------
// Kernel 3: S_i = sum_h rowpart[h][i] + sum_s colpart[s][i];
// loss_i = log(S_i) + (1-pos_i)/T ; out = mean (32 atomic partials).
// ---------------------------------------------------------------------------
__global__ __launch_bounds__(256) void finalize_kernel(
    const float* __restrict__ rowpart, const float* __restrict__ colpart,
    const float* __restrict__ posv, float* __restrict__ out) {
  __shared__ float red[4];
  const int i = blockIdx.x * 256 + threadIdx.x;
  float S = 0.0f;
#pragma unroll
  for (int hh = 0; hh < 8; ++hh) S += rowpart[(size_t)hh * NROW + i];
#pragma unroll
  for (int ss = 0; ss < 32; ++ss) S += colpart[(size_t)ss * NROW + i];
  float l = __logf(S) + (1.0f - posv[i]) * INV_T;
#pragma unroll
  for (int off = 32; off > 0; off >>= 1) l += __shfl_down(l, off);
  if ((threadIdx.x & 63) == 0) red[threadIdx.x >> 6] = l;
  __syncthreads();
  if (threadIdx.x == 0)
    atomicAdd(out, (red[0] + red[1] + red[2] + red[3]) * (1.0f / NROW));
}

// ---------------------------------------------------------------------------
extern "C" void kernel_launch(void* const* d_in, const int* in_sizes, int n_in,
                              void* d_out, int out_size, void* d_ws, size_t ws_size,
                              hipStream_t stream) {
  const float* v1 = (const float*)d_in[0];
  const float* v2 = (const float*)d_in[1];
  float* out = (float*)d_out;

  __hip_bfloat16* e = (__hip_bfloat16*)d_ws;          // NROW*DIM bf16 (2 MB)
  float* rowpart = (float*)(e + (size_t)NROW * DIM);  // 8*NROW floats
  float* colpart = rowpart + (size_t)8 * NROW;        // 32*NROW floats
  float* posv    = colpart + (size_t)32 * NROW;       // NROW floats

  normalize_kernel<<<NROW / 4, 256, 0, stream>>>(v1, v2, e, colpart, out);
  dim3 grid(64, 8);
  sim_kernel<<<grid, 256, 0, stream>>>((const ushort*)e, rowpart, colpart,
                                       posv);
  finalize_kernel<<<32, 256, 0, stream>>>(rowpart, colpart, posv, out);
}